// Round 1
// baseline (807.832 us; speedup 1.0000x reference)
//
#include <hip/hip_runtime.h>
#include <math.h>

// ---------------------------------------------------------------------------
// Problem: loss = CE(logits, targets) + CRL(conf ranking) + MDCA(calibration)
// B=4096, C=32000. Two streaming passes over logits (524 MB each) + finalize.
// ---------------------------------------------------------------------------

// Pass 1: one block per row. Online softmax (running max + rescaled sum) in
// registers, float4 global loads. Emits rowm[b], rowinv[b] = 1/sumexp (which
// equals max softmax prob), celogp[b] = logp[b, target[b]], and a float
// histogram of targets via one atomic per row.
__global__ __launch_bounds__(256) void pass1_kernel(
    const float* __restrict__ logits, const int* __restrict__ targets,
    float* __restrict__ rowm, float* __restrict__ rowinv,
    float* __restrict__ celogp, float* __restrict__ counts, int C)
{
    const int b   = blockIdx.x;
    const int tid = threadIdx.x;
    const float* row = logits + (size_t)b * (size_t)C;

    float m = -INFINITY, s = 0.0f;
    const int n4 = C >> 2;
    const float4* row4 = (const float4*)row;
    for (int i = tid; i < n4; i += 256) {
        float4 v = row4[i];
        float vm = fmaxf(fmaxf(v.x, v.y), fmaxf(v.z, v.w));
        float nm = fmaxf(m, vm);
        s = s * __expf(m - nm)
          + __expf(v.x - nm) + __expf(v.y - nm)
          + __expf(v.z - nm) + __expf(v.w - nm);
        m = nm;
    }
    for (int i = (n4 << 2) + tid; i < C; i += 256) {  // tail (unused: C%4==0)
        float v = row[i];
        float nm = fmaxf(m, v);
        s = s * __expf(m - nm) + __expf(v - nm);
        m = nm;
    }

    // wave (64-lane) reduce of (m, s) with rescaling
    for (int off = 32; off; off >>= 1) {
        float om = __shfl_down(m, off, 64);
        float os = __shfl_down(s, off, 64);
        float nm = fmaxf(m, om);
        s = s * __expf(m - nm) + os * __expf(om - nm);
        m = nm;
    }
    __shared__ float sm[4], ss[4];
    const int wid = tid >> 6, lane = tid & 63;
    if (lane == 0) { sm[wid] = m; ss[wid] = s; }
    __syncthreads();
    if (tid == 0) {
        m = sm[0]; s = ss[0];
        #pragma unroll
        for (int w = 1; w < 4; ++w) {
            float om = sm[w], os = ss[w];
            float nm = fmaxf(m, om);
            s = s * __expf(m - nm) + os * __expf(om - nm);
            m = nm;
        }
        rowm[b]   = m;
        rowinv[b] = 1.0f / s;          // == max softmax probability
        int t = targets[b];
        celogp[b] = row[t] - m - logf(s);
        atomicAdd(&counts[t], 1.0f);
    }
}

// Pass 2: column sums of softmax probabilities.
// Grid: (ceil(C/2048) column chunks, B/RPG row groups). Each thread owns 8
// columns (two float4 slots) accumulated in registers over RPG rows, then 8
// atomics into colsum. rowm/rowinv staged in LDS per group.
#define RPG 64
__global__ __launch_bounds__(256) void pass2_kernel(
    const float* __restrict__ logits, const float* __restrict__ rowm,
    const float* __restrict__ rowinv, float* __restrict__ colsum,
    int B, int C)
{
    const int tid  = threadIdx.x;
    const int base = blockIdx.x * 2048;
    const int ncols = min(2048, C - base);
    const int c0 = base + (tid << 2);
    const int c1 = base + 1024 + (tid << 2);
    const bool v0 = (tid << 2) < ncols;
    const bool v1 = (1024 + (tid << 2)) < ncols;

    __shared__ float smem_m[RPG], smem_i[RPG];
    const int r0 = blockIdx.y * RPG;
    const int nr = min(RPG, B - r0);
    if (tid < nr) { smem_m[tid] = rowm[r0 + tid]; smem_i[tid] = rowinv[r0 + tid]; }
    __syncthreads();

    float4 a0 = make_float4(0.f, 0.f, 0.f, 0.f);
    float4 a1 = make_float4(0.f, 0.f, 0.f, 0.f);
    #pragma unroll 4
    for (int r = 0; r < nr; ++r) {
        const float mm = smem_m[r];
        const float iv = smem_i[r];
        const float* row = logits + (size_t)(r0 + r) * (size_t)C;
        if (v0) {
            float4 v = *(const float4*)(row + c0);
            a0.x += __expf(v.x - mm) * iv;
            a0.y += __expf(v.y - mm) * iv;
            a0.z += __expf(v.z - mm) * iv;
            a0.w += __expf(v.w - mm) * iv;
        }
        if (v1) {
            float4 v = *(const float4*)(row + c1);
            a1.x += __expf(v.x - mm) * iv;
            a1.y += __expf(v.y - mm) * iv;
            a1.z += __expf(v.z - mm) * iv;
            a1.w += __expf(v.w - mm) * iv;
        }
    }
    if (v0) {
        atomicAdd(&colsum[c0 + 0], a0.x);
        atomicAdd(&colsum[c0 + 1], a0.y);
        atomicAdd(&colsum[c0 + 2], a0.z);
        atomicAdd(&colsum[c0 + 3], a0.w);
    }
    if (v1) {
        atomicAdd(&colsum[c1 + 0], a1.x);
        atomicAdd(&colsum[c1 + 1], a1.y);
        atomicAdd(&colsum[c1 + 2], a1.z);
        atomicAdd(&colsum[c1 + 3], a1.w);
    }
}

// Finalize: one block. CE mean, CRL margin-ranking loss, MDCA mean-abs.
__global__ __launch_bounds__(1024) void final_kernel(
    const float* __restrict__ rowinv, const float* __restrict__ celogp,
    const int* __restrict__ idx, const int* __restrict__ targets_unused,
    const float* __restrict__ correctness,
    const float* __restrict__ colsum, const float* __restrict__ counts,
    float* __restrict__ out, int B, int C)
{
    const int tid = threadIdx.x;
    float sum_ce = 0.f, sum_crl = 0.f, sum_cal = 0.f;

    for (int b = tid; b < B; b += 1024) {
        sum_ce += celogp[b];
        const int b2 = (b + 1 == B) ? 0 : b + 1;
        const float conf  = rowinv[b];
        const float conf2 = rowinv[b2];
        const float c1 = correctness[idx[b]];
        const float c2 = correctness[idx[b2]];
        const float rt  = (c1 > c2) ? 1.f : ((c1 < c2) ? -1.f : 0.f);
        const float rm  = fabsf(c1 - c2);
        const float tnz = (rt == 0.f) ? 1.f : rt;
        const float ri2 = conf2 + rm / tnz;
        sum_crl += fmaxf(0.f, -rt * (conf - ri2));
    }
    for (int c = tid; c < C; c += 1024) {
        sum_cal += fabsf(colsum[c] - counts[c]);
    }

    for (int off = 32; off; off >>= 1) {
        sum_ce  += __shfl_down(sum_ce,  off, 64);
        sum_crl += __shfl_down(sum_crl, off, 64);
        sum_cal += __shfl_down(sum_cal, off, 64);
    }
    __shared__ float red[3][16];
    const int wid = tid >> 6, lane = tid & 63;
    if (lane == 0) { red[0][wid] = sum_ce; red[1][wid] = sum_crl; red[2][wid] = sum_cal; }
    __syncthreads();
    if (tid == 0) {
        float tce = 0.f, tcrl = 0.f, tcal = 0.f;
        #pragma unroll
        for (int w = 0; w < 16; ++w) { tce += red[0][w]; tcrl += red[1][w]; tcal += red[2][w]; }
        const float loss_cls = -tce / (float)B;
        const float loss_ref = tcrl / (float)B;
        const float loss_cal = tcal / ((float)B * (float)C);
        out[0] = loss_cls + loss_ref + loss_cal;  // GAMMA = BETA = 1
    }
}

extern "C" void kernel_launch(void* const* d_in, const int* in_sizes, int n_in,
                              void* d_out, int out_size, void* d_ws, size_t ws_size,
                              hipStream_t stream) {
    const float* logits      = (const float*)d_in[0];
    const int*   targets     = (const int*)d_in[1];
    const int*   idx         = (const int*)d_in[2];
    const float* correctness = (const float*)d_in[3];
    float* out = (float*)d_out;

    const int B = in_sizes[1];
    const int C = in_sizes[0] / B;

    // workspace layout (all fp32): rowm[B] | rowinv[B] | celogp[B] | colsum[C] | counts[C]
    char* ws = (char*)d_ws;
    float* rowm   = (float*)ws;                      ws += (size_t)B * sizeof(float);
    float* rowinv = (float*)ws;                      ws += (size_t)B * sizeof(float);
    float* celogp = (float*)ws;                      ws += (size_t)B * sizeof(float);
    float* colsum = (float*)ws;                      ws += (size_t)C * sizeof(float);
    float* counts = (float*)ws;

    hipMemsetAsync(colsum, 0, (size_t)C * sizeof(float), stream);
    hipMemsetAsync(counts, 0, (size_t)C * sizeof(float), stream);

    pass1_kernel<<<B, 256, 0, stream>>>(logits, targets, rowm, rowinv, celogp, counts, C);

    dim3 g2((C + 2047) / 2048, (B + RPG - 1) / RPG);
    pass2_kernel<<<g2, 256, 0, stream>>>(logits, rowm, rowinv, colsum, B, C);

    final_kernel<<<1, 1024, 0, stream>>>(rowinv, celogp, idx, targets, correctness,
                                         colsum, counts, out, B, C);
}